// Round 3
// baseline (145.121 us; speedup 1.0000x reference)
//
#include <hip/hip_runtime.h>
#include <stdint.h>

#define VSZ 30000
#define TPS 2048      // trees per side
#define G3  384

// workspace layout (float offsets)
#define OFF_PROJ   0u          // 30000*128 bf16 = 1,920,000 floats
#define OFF_WCT    1920000u    // 128*128
#define OFF_WIHTF  1936384u    // 128*384
#define OFF_WIHTB  1985536u    // 128*384
#define OFF_SEQ    2034688u    // 2*2048*128
#define OFF_GI     2558976u    // 4*64*32*384
#define OFF_HFIN   5704704u    // 256*128

using f32x4 = __attribute__((ext_vector_type(4))) float;
using s16x8 = __attribute__((ext_vector_type(8))) short;
union U8 { uint4 u; s16x8 s; };

__device__ __forceinline__ float sigm(float x) { return 1.0f / (1.0f + __expf(-x)); }
__device__ __forceinline__ float tanh_fast(float x) {
  float e = __expf(-2.0f * x);
  return 2.0f / (1.0f + e) - 1.0f;   // safe at both tails (no inf/inf)
}
__device__ __forceinline__ unsigned bf16_rn(float f) {
  unsigned u = __float_as_uint(f);
  return (u + 0x7FFFu + ((u >> 16) & 1u)) >> 16;   // round-to-nearest-even
}

// ---- K0: transpose three [R][128] -> [128][R] in one launch
__global__ __launch_bounds__(256) void k_transpose3(const float* __restrict__ w_c,
                                                    const float* __restrict__ wf,
                                                    const float* __restrict__ wb,
                                                    float* __restrict__ dwc,
                                                    float* __restrict__ dwf,
                                                    float* __restrict__ dwb) {
  __shared__ float tile[32][129];
  int b = blockIdx.x;
  const float* src; float* dst; int R, r0;
  if (b < 4)       { src = w_c; dst = dwc; R = 128; r0 = b * 32; }
  else if (b < 16) { src = wf;  dst = dwf; R = 384; r0 = (b - 4) * 32; }
  else             { src = wb;  dst = dwb; R = 384; r0 = (b - 16) * 32; }
  for (int idx = threadIdx.x; idx < 32 * 128; idx += 256) {
    int r = idx >> 7, c = idx & 127;
    tile[r][c] = src[(r0 + r) * 128 + c];
  }
  __syncthreads();
  for (int idx = threadIdx.x; idx < 32 * 128; idx += 256) {
    int k = idx >> 5, r = idx & 31;
    dst[k * R + r0 + r] = tile[r][k];
  }
}

// ---- K1: proj[v][eo] = b_c[eo] + sum_k emb[v][k] * w_c[eo][k]; output bf16
__global__ __launch_bounds__(256) void k_proj(const float* __restrict__ emb,
                                              const float* __restrict__ wcT,
                                              const float* __restrict__ b_c,
                                              unsigned short* __restrict__ projb) {
  __shared__ float wT[128 * 128];     // 64 KB, [k][eo]
  __shared__ float es[32][128];       // 16 KB
  int v0 = blockIdx.x * 32;
  for (int idx = threadIdx.x; idx < 128 * 32; idx += 256)
    ((float4*)wT)[idx] = ((const float4*)wcT)[idx];
  for (int idx = threadIdx.x; idx < 32 * 32; idx += 256) {
    int v = idx >> 5;
    float4 val = make_float4(0.f, 0.f, 0.f, 0.f);
    if (v0 + v < VSZ) val = ((const float4*)emb)[v0 * 32 + idx];
    ((float4*)es)[idx] = val;
  }
  __syncthreads();
  int tv = (threadIdx.x >> 5) << 2;   // v base (0..28)
  int te = (threadIdx.x & 31) << 2;   // eo base (0..124)
  float4 bc4 = *(const float4*)&b_c[te];
  float4 a0 = bc4, a1 = bc4, a2 = bc4, a3 = bc4;
#pragma unroll 4
  for (int kk = 0; kk < 128; ++kk) {
    float4 w4 = *(float4*)&wT[kk * 128 + te];
    float e0 = es[tv + 0][kk], e1 = es[tv + 1][kk];
    float e2 = es[tv + 2][kk], e3 = es[tv + 3][kk];
    a0.x = fmaf(e0, w4.x, a0.x); a0.y = fmaf(e0, w4.y, a0.y);
    a0.z = fmaf(e0, w4.z, a0.z); a0.w = fmaf(e0, w4.w, a0.w);
    a1.x = fmaf(e1, w4.x, a1.x); a1.y = fmaf(e1, w4.y, a1.y);
    a1.z = fmaf(e1, w4.z, a1.z); a1.w = fmaf(e1, w4.w, a1.w);
    a2.x = fmaf(e2, w4.x, a2.x); a2.y = fmaf(e2, w4.y, a2.y);
    a2.z = fmaf(e2, w4.z, a2.z); a2.w = fmaf(e2, w4.w, a2.w);
    a3.x = fmaf(e3, w4.x, a3.x); a3.y = fmaf(e3, w4.y, a3.y);
    a3.z = fmaf(e3, w4.z, a3.z); a3.w = fmaf(e3, w4.w, a3.w);
  }
#pragma unroll
  for (int i = 0; i < 4; ++i) {
    float4 a = (i == 0) ? a0 : (i == 1) ? a1 : (i == 2) ? a2 : a3;
    int v = v0 + tv + i;
    if (v < VSZ) {
      uint2 u;
      u.x = bf16_rn(a.x) | (bf16_rn(a.y) << 16);
      u.y = bf16_rn(a.z) | (bf16_rn(a.w) << 16);
      *(uint2*)&projb[(size_t)v * 128 + te] = u;
    }
  }
}

// ---- K2: per-tree subtree sums (heap), coord-wise max, ReLU -> seq[side][t][c]
__global__ __launch_bounds__(256) void k_tree(const int* __restrict__ tokens1,
                                              const int* __restrict__ tokens2,
                                              const unsigned short* __restrict__ projb,
                                              float* __restrict__ seq) {
  __shared__ int tok[2][64];
  int side = blockIdx.y;
  const int* tokens = side ? tokens2 : tokens1;
  int t0 = blockIdx.x * 2;
  if (threadIdx.x < 128) {
    int tl = threadIdx.x >> 6, j = threadIdx.x & 63;
    tok[tl][j] = tokens[(t0 + tl) * 64 + j];
  }
  __syncthreads();
  int tl = threadIdx.x >> 7;
  int c  = threadIdx.x & 127;
  float s[64];
#pragma unroll
  for (int j = 0; j < 64; ++j)
    s[j] = __uint_as_float(((unsigned)projb[(size_t)tok[tl][j] * 128 + c]) << 16);
  // bottom-up subtree sums: children of j are 2j+1, 2j+2 (node 31 has only 63)
  s[31] += s[63];
#pragma unroll
  for (int j = 30; j >= 0; --j) s[j] += s[2 * j + 1] + s[2 * j + 2];
  float m = s[0];
#pragma unroll
  for (int j = 1; j < 64; ++j) m = fmaxf(m, s[j]);
  m = fmaxf(m, 0.0f);
  seq[(size_t)(side * TPS + t0 + tl) * 128 + c] = m;
}

// ---- K3: gi[side][dir][b][s][r] = b_ih[r] + sum_k seq[side][t][k]*w_ih[r][k]
__global__ __launch_bounds__(256) void k_gi(const float* __restrict__ seq,
                                            const float* __restrict__ wihT_f,
                                            const float* __restrict__ wihT_b,
                                            const float* __restrict__ b_ih_f,
                                            const float* __restrict__ b_ih_b,
                                            float* __restrict__ gi) {
  __shared__ float wT[128 * 128];   // [k][r-chunk]
  __shared__ float sq[16][128];
  int ttile = blockIdx.x;           // 0..127
  int rc = blockIdx.y;              // 0..2
  int sd = blockIdx.z;              // side*2+dir
  int side = sd >> 1, dir = sd & 1;
  const float* wihT = dir ? wihT_b : wihT_f;
  const float* b_ih = dir ? b_ih_b : b_ih_f;
  for (int idx = threadIdx.x; idx < 128 * 32; idx += 256) {
    int k = idx >> 5, r4 = idx & 31;
    ((float4*)wT)[idx] = *(const float4*)&wihT[k * G3 + rc * 128 + (r4 << 2)];
  }
  int t0 = ttile * 16;
  const float4* sqsrc = (const float4*)&seq[(size_t)(side * TPS + t0) * 128];
  for (int idx = threadIdx.x; idx < 16 * 32; idx += 256)
    ((float4*)sq)[idx] = sqsrc[idx];
  __syncthreads();
  int tt = threadIdx.x >> 5;        // t-pair 0..7
  int te = (threadIdx.x & 31) << 2; // r base
  float4 b4 = *(const float4*)&b_ih[rc * 128 + te];
  float4 a0 = b4, a1 = b4;
#pragma unroll 4
  for (int kk = 0; kk < 128; ++kk) {
    float4 w4 = *(float4*)&wT[kk * 128 + te];
    float e0 = sq[tt * 2 + 0][kk], e1 = sq[tt * 2 + 1][kk];
    a0.x = fmaf(e0, w4.x, a0.x); a0.y = fmaf(e0, w4.y, a0.y);
    a0.z = fmaf(e0, w4.z, a0.z); a0.w = fmaf(e0, w4.w, a0.w);
    a1.x = fmaf(e1, w4.x, a1.x); a1.y = fmaf(e1, w4.y, a1.y);
    a1.z = fmaf(e1, w4.z, a1.z); a1.w = fmaf(e1, w4.w, a1.w);
  }
#pragma unroll
  for (int i = 0; i < 2; ++i) {
    int t = t0 + tt * 2 + i;
    int b = t >> 5, s = t & 31;
    float4 v = i ? a1 : a0;
    *(float4*)&gi[((size_t)(sd * 64 + b) * 32 + s) * G3 + rc * 128 + te] = v;
  }
}

// ---- K4: GRU scans via MFMA, 16 programs per block.
//      grid = 16 blocks: blockIdx.x = (pg<<2)|sd, sd = side*2+dir, pg = program
//      group (16 programs). 512 threads = 8 waves. Wave w holds A-fragments
//      (bf16, registers) of w_hh rows {g*128+16w .. +15} for g in {r,z,n}.
//      Per step: B-frag = h[128 x 16programs] bf16 from LDS (4KB, dbuf),
//      12 MFMA (3 gates x 4 ktiles), in-lane gate combine (D: col=lane&15=
//      program, row=(lane>>4)*4+reg = h-col), h carried f32 in registers.
//      One barrier per step.
__global__ __launch_bounds__(512) void k_scan(const float* __restrict__ gi,
                                              const float* __restrict__ w_hh_f,
                                              const float* __restrict__ w_hh_b,
                                              const float* __restrict__ b_hh_f,
                                              const float* __restrict__ b_hh_b,
                                              float* __restrict__ hfin) {
  __shared__ __align__(16) unsigned hbuf[2][1024];   // 2 x 4KB bf16 B-frag buffers
  int bx = blockIdx.x;
  int sd = bx & 3, pg = bx >> 2;
  int dir = sd & 1;
  const float* whh = dir ? w_hh_b : w_hh_f;
  const float* bhh = dir ? b_hh_b : b_hh_f;
  int tid = threadIdx.x;
  int w = tid >> 6, l = tid & 63;
  int p  = l & 15;          // program (MFMA n / D col)
  int kb = l >> 4;          // k-block within fragment
  int c0 = 16 * w + 4 * kb; // D-row base: h-columns c0..c0+3 for this lane

  for (int i = tid; i < 2048; i += 512) ((unsigned*)hbuf)[i] = 0u;

  // ---- persistent A-fragments: lane holds A[m=p][k=kb*8+j] of each 16x32 tile
  s16x8 aw[3][4];
#pragma unroll
  for (int g = 0; g < 3; ++g)
#pragma unroll
    for (int t = 0; t < 4; ++t) {
      int row = g * 128 + 16 * w + p;
      int ks  = t * 32 + kb * 8;
      float4 f0 = *(const float4*)&whh[row * 128 + ks];
      float4 f1 = *(const float4*)&whh[row * 128 + ks + 4];
      U8 u;
      u.u.x = bf16_rn(f0.x) | (bf16_rn(f0.y) << 16);
      u.u.y = bf16_rn(f0.z) | (bf16_rn(f0.w) << 16);
      u.u.z = bf16_rn(f1.x) | (bf16_rn(f1.y) << 16);
      u.u.w = bf16_rn(f1.z) | (bf16_rn(f1.w) << 16);
      aw[g][t] = u.s;
    }
  f32x4 bh[3];
#pragma unroll
  for (int g = 0; g < 3; ++g) bh[g] = *(const f32x4*)&bhh[g * 128 + c0];

  const float* gbase = gi + (size_t)(sd * 64 + pg * 16 + p) * (32 * G3);
  // h-write position (B-frag layout: value for (k=c,n=p) sits at lane
  // l'=p+16*((c&31)>>3), j=c&7, ktile c>>5)
  int tw = c0 >> 5;
  int l2 = p + 16 * ((c0 & 31) >> 3);
  int jo = c0 & 7;
  char* wb0 = (char*)hbuf + tw * 1024 + l2 * 16 + jo * 2;

  float hc[4] = {0.f, 0.f, 0.f, 0.f};
  int o0 = (dir ? 31 : 0) * G3;
  f32x4 gv[3];
#pragma unroll
  for (int g = 0; g < 3; ++g) gv[g] = *(const f32x4*)&gbase[o0 + g * 128 + c0];
  __syncthreads();

  for (int s = 0; s < 32; ++s) {
    const char* bb = (const char*)hbuf + (s & 1) * 4096;
    s16x8 bf[4];
#pragma unroll
    for (int t = 0; t < 4; ++t) {
      U8 u; u.u = *(const uint4*)(bb + t * 1024 + l * 16);
      bf[t] = u.s;
    }
    f32x4 aR = {0.f, 0.f, 0.f, 0.f}, aZ = aR, aN = aR;
#pragma unroll
    for (int t = 0; t < 4; ++t) {
      aR = __builtin_amdgcn_mfma_f32_16x16x32_bf16(aw[0][t], bf[t], aR, 0, 0, 0);
      aZ = __builtin_amdgcn_mfma_f32_16x16x32_bf16(aw[1][t], bf[t], aZ, 0, 0, 0);
      aN = __builtin_amdgcn_mfma_f32_16x16x32_bf16(aw[2][t], bf[t], aN, 0, 0, 0);
    }
    f32x4 gn[3];
    if (s < 31) {
      int o = (dir ? (30 - s) : (s + 1)) * G3;
#pragma unroll
      for (int g = 0; g < 3; ++g) gn[g] = *(const f32x4*)&gbase[o + g * 128 + c0];
    }
#pragma unroll
    for (int reg = 0; reg < 4; ++reg) {
      float rv = sigm(gv[0][reg] + aR[reg] + bh[0][reg]);
      float zv = sigm(gv[1][reg] + aZ[reg] + bh[1][reg]);
      float nv = tanh_fast(gv[2][reg] + rv * (aN[reg] + bh[2][reg]));
      hc[reg] = (1.0f - zv) * nv + zv * hc[reg];
    }
    uint2 hp;
    hp.x = bf16_rn(hc[0]) | (bf16_rn(hc[1]) << 16);
    hp.y = bf16_rn(hc[2]) | (bf16_rn(hc[3]) << 16);
    *(uint2*)(wb0 + ((s + 1) & 1) * 4096) = hp;
    __syncthreads();
#pragma unroll
    for (int g = 0; g < 3; ++g) gv[g] = gn[g];
  }
  int scan = sd * 64 + pg * 16 + p;
#pragma unroll
  for (int reg = 0; reg < 4; ++reg)
    hfin[(size_t)scan * 128 + c0 + reg] = hc[reg];
}

// ---- K5: out[b] = sigmoid(|lvec-rvec| . w_out + b_out)
__global__ __launch_bounds__(64) void k_out(const float* __restrict__ hfin,
                                            const float* __restrict__ w_out,
                                            const float* __restrict__ b_out,
                                            float* __restrict__ out) {
  int b = blockIdx.x, lane = threadIdx.x;
  float p = 0.f;
#pragma unroll
  for (int i = 0; i < 2; ++i) {
    int c = lane + i * 64;
    float l = hfin[(size_t)(0   + b) * 128 + c] + hfin[(size_t)(64  + b) * 128 + c];
    float r = hfin[(size_t)(128 + b) * 128 + c] + hfin[(size_t)(192 + b) * 128 + c];
    p += fabsf(l - r) * w_out[c];
  }
#pragma unroll
  for (int off = 32; off > 0; off >>= 1) p += __shfl_down(p, off);
  if (lane == 0) out[b] = sigm(p + b_out[0]);
}

extern "C" void kernel_launch(void* const* d_in, const int* in_sizes, int n_in,
                              void* d_out, int out_size, void* d_ws, size_t ws_size,
                              hipStream_t stream) {
  (void)in_sizes; (void)n_in; (void)out_size; (void)ws_size;
  const int*   tokens1 = (const int*)d_in[0];
  const int*   tokens2 = (const int*)d_in[2];
  const float* emb     = (const float*)d_in[4];
  const float* w_c     = (const float*)d_in[5];
  const float* b_c     = (const float*)d_in[6];
  const float* w_ih_f  = (const float*)d_in[7];
  const float* w_hh_f  = (const float*)d_in[8];
  const float* b_ih_f  = (const float*)d_in[9];
  const float* b_hh_f  = (const float*)d_in[10];
  const float* w_ih_b  = (const float*)d_in[11];
  const float* w_hh_b  = (const float*)d_in[12];
  const float* b_ih_b  = (const float*)d_in[13];
  const float* b_hh_b  = (const float*)d_in[14];
  const float* w_out   = (const float*)d_in[15];
  const float* b_out   = (const float*)d_in[16];
  float* ws = (float*)d_ws;
  unsigned short* projb = (unsigned short*)(ws + OFF_PROJ);
  float* wcT    = ws + OFF_WCT;
  float* wihT_f = ws + OFF_WIHTF;
  float* wihT_b = ws + OFF_WIHTB;
  float* seq    = ws + OFF_SEQ;
  float* gi     = ws + OFF_GI;
  float* hfin   = ws + OFF_HFIN;

  k_transpose3<<<28, 256, 0, stream>>>(w_c, w_ih_f, w_ih_b, wcT, wihT_f, wihT_b);
  k_proj<<<(VSZ + 31) / 32, 256, 0, stream>>>(emb, wcT, b_c, projb);
  k_tree<<<dim3(TPS / 2, 2), 256, 0, stream>>>(tokens1, tokens2, projb, seq);
  k_gi<<<dim3(128, 3, 4), 256, 0, stream>>>(seq, wihT_f, wihT_b, b_ih_f, b_ih_b, gi);
  k_scan<<<16, 512, 0, stream>>>(gi, w_hh_f, w_hh_b, b_hh_f, b_hh_b, hfin);
  k_out<<<64, 64, 0, stream>>>(hfin, w_out, b_out, (float*)d_out);
}